// Round 4
// baseline (1117.989 us; speedup 1.0000x reference)
//
#include <hip/hip_runtime.h>

#define NUM_ITEM 500000
#define EMBED_DIM 64
#define SPAN 256                                  // items per bucket
#define NB_BUCKET ((NUM_ITEM + SPAN - 1) / SPAN)  // 1954
#define NSUB 8                                    // XCD-local sublists per bucket

typedef float f4_native __attribute__((ext_vector_type(4)));

// ---------------- tier-0: bucketed fused pipeline ----------------

// Pass 1: bin edges by dst>>8 into (bucket, blockIdx&7) sublists.
// Record packed to 4B: (d & 255) << 24 | s   (valid: s < 2^20 < 2^24).
// Write frontier = 15632 sublist tails (~1MB), each line filled by ~16
// sequential writes from one XCD's blocks -> writebacks ~= payload (8MB),
// unlike the random 16-32MB pad scatter (128MB writebacks, R1/R3).
__global__ __launch_bounds__(256) void bin_edges(
    const int* __restrict__ edge_src, const int* __restrict__ edge_dst,
    int num_edges, int* __restrict__ cur, unsigned* __restrict__ storage,
    int subcap, uint2* __restrict__ spill, int* __restrict__ spill_n,
    int spill_cap)
{
    int e = blockIdx.x * 256 + threadIdx.x;
    if (e >= num_edges) return;
    int d = edge_dst[e];
    int s = edge_src[e];
    int idx = ((d >> 8) << 3) + (blockIdx.x & 7);
    int pos = atomicAdd(&cur[idx], 1);
    if (pos < subcap) {
        storage[(size_t)idx * subcap + pos] =
            ((unsigned)(d & 255) << 24) | (unsigned)s;
    } else {
        int o = atomicAdd(spill_n, 1);
        if (o < spill_cap) { spill[o] = make_uint2((unsigned)d, (unsigned)s); }
    }
}

// Pass 2: one 256-thread WG per bucket. Sums for 256 items x 64 dims live
// in LDS (64KB); lane = dim so ds_add_f32 is bank-conflict-free. 8-deep
// unroll gives 8 independent row fetches in flight per wave (16 waves/CU
// at 2 WGs/CU). Counts in LDS too -> no global cnt, no big memset.
__global__ __launch_bounds__(256) void bucket_reduce(
    const float* __restrict__ user_embed, const int* __restrict__ cur,
    const unsigned* __restrict__ storage, int subcap,
    const uint2* __restrict__ spill, const int* __restrict__ spill_n,
    int spill_cap, float* __restrict__ out, int n_items)
{
    __shared__ float acc[SPAN * EMBED_DIM];   // 64 KB
    __shared__ int   lcnt[SPAN];
    const int b    = blockIdx.x;
    const int tid  = threadIdx.x;
    const int wid  = tid >> 6;
    const int lane = tid & 63;

    f4_native z = 0.0f;
    f4_native* a4 = (f4_native*)acc;
#pragma unroll
    for (int i = 0; i < (SPAN * EMBED_DIM / 4) / 256; ++i)   // 16 iters
        a4[tid + i * 256] = z;
    lcnt[tid] = 0;
    __syncthreads();

    const int item0 = b << 8;
    for (int sub = 0; sub < NSUB; ++sub) {
        const int idx = (b << 3) + sub;
        int ne = cur[idx]; if (ne > subcap) ne = subcap;
        const unsigned* base = storage + (size_t)idx * subcap;
        int e = wid;
        for (; e + 28 < ne; e += 32) {           // 8 edges per wave per iter
            unsigned r[8]; float v[8];
#pragma unroll
            for (int k = 0; k < 8; ++k) r[k] = base[e + 4 * k];
#pragma unroll
            for (int k = 0; k < 8; ++k)
                v[k] = user_embed[((size_t)(r[k] & 0xFFFFFFu) << 6) + lane];
#pragma unroll
            for (int k = 0; k < 8; ++k) {
                int dl = r[k] >> 24;
                atomicAdd(&acc[(dl << 6) + lane], v[k]);
                if (lane == 0) atomicAdd(&lcnt[dl], 1);
            }
        }
        for (; e < ne; e += 4) {
            unsigned r = base[e];
            float v = user_embed[((size_t)(r & 0xFFFFFFu) << 6) + lane];
            int dl = r >> 24;
            atomicAdd(&acc[(dl << 6) + lane], v);
            if (lane == 0) atomicAdd(&lcnt[dl], 1);
        }
    }

    // spill entries (normally zero) — exactness for any input
    int ns = *spill_n; if (ns > spill_cap) ns = spill_cap;
    for (int i = wid; i < ns; i += 4) {
        uint2 p = spill[i];
        int d = (int)p.x;
        if (d >= item0 && d < item0 + SPAN) {
            int dl = d - item0;
            float v = user_embed[((size_t)p.y << 6) + lane];
            atomicAdd(&acc[(dl << 6) + lane], v);
            if (lane == 0) atomicAdd(&lcnt[dl], 1);
        }
    }
    __syncthreads();

    for (int it = wid; it < SPAN; it += 4) {
        int item = item0 + it;
        if (item >= n_items) break;              // wave-uniform
        float c = (float)lcnt[it];
        float v = acc[(it << 6) + lane] / fmaxf(c, 1.0f);
        // coalesced 256B per wave; nontemporal: don't let the 128MB output
        // stream evict user rows from L2
        __builtin_nontemporal_store(v, &out[((size_t)item << 6) + lane]);
    }
}

// ---------------- tier-2: exact CSR pipeline (fallback) ----------------

__global__ __launch_bounds__(256) void histogram_dst(
    const int* __restrict__ edge_dst, int num_edges, int* __restrict__ counts)
{
    int e = blockIdx.x * blockDim.x + threadIdx.x;
    if (e >= num_edges) return;
    atomicAdd(&counts[edge_dst[e]], 1);
}

__global__ __launch_bounds__(256) void block_sums(
    const int* __restrict__ counts, int n, int* __restrict__ partials)
{
    __shared__ int red[256];
    int i = blockIdx.x * 256 + threadIdx.x;
    red[threadIdx.x] = (i < n) ? counts[i] : 0;
    __syncthreads();
    for (int s = 128; s > 0; s >>= 1) {
        if (threadIdx.x < (unsigned)s) red[threadIdx.x] += red[threadIdx.x + s];
        __syncthreads();
    }
    if (threadIdx.x == 0) partials[blockIdx.x] = red[0];
}

__global__ __launch_bounds__(256) void scan_partials(int* __restrict__ partials, int nb)
{
    __shared__ int tmp[256];
    __shared__ int carry_s;
    if (threadIdx.x == 0) carry_s = 0;
    __syncthreads();
    for (int base = 0; base < nb; base += 256) {
        int i = base + threadIdx.x;
        int v = (i < nb) ? partials[i] : 0;
        tmp[threadIdx.x] = v;
        __syncthreads();
        for (int off = 1; off < 256; off <<= 1) {
            int t = (threadIdx.x >= (unsigned)off) ? tmp[threadIdx.x - off] : 0;
            __syncthreads();
            tmp[threadIdx.x] += t;
            __syncthreads();
        }
        int incl = tmp[threadIdx.x];
        int c = carry_s;
        if (i < nb) partials[i] = incl - v + c;
        __syncthreads();
        if (threadIdx.x == 255) carry_s = c + tmp[255];
        __syncthreads();
    }
}

__global__ __launch_bounds__(256) void make_offsets(
    const int* __restrict__ counts, const int* __restrict__ partials, int n,
    int* __restrict__ offsets, int* __restrict__ cursor)
{
    __shared__ int tmp[256];
    int i = blockIdx.x * 256 + threadIdx.x;
    int v = (i < n) ? counts[i] : 0;
    tmp[threadIdx.x] = v;
    __syncthreads();
    for (int off = 1; off < 256; off <<= 1) {
        int t = (threadIdx.x >= (unsigned)off) ? tmp[threadIdx.x - off] : 0;
        __syncthreads();
        tmp[threadIdx.x] += t;
        __syncthreads();
    }
    int excl = tmp[threadIdx.x] - v + partials[blockIdx.x];
    if (i < n) { offsets[i] = excl; cursor[i] = excl; }
}

__global__ __launch_bounds__(256) void scatter_csr(
    const int* __restrict__ edge_src, const int* __restrict__ edge_dst,
    int num_edges, int* __restrict__ cursor, int* __restrict__ csr_src)
{
    int e = blockIdx.x * blockDim.x + threadIdx.x;
    if (e >= num_edges) return;
    int d = edge_dst[e];
    int pos = atomicAdd(&cursor[d], 1);
    csr_src[pos] = edge_src[e];
}

__global__ __launch_bounds__(256) void gather_mean(
    const float* __restrict__ user_embed, const int* __restrict__ csr_src,
    const int* __restrict__ offsets, const int* __restrict__ counts,
    float* __restrict__ out, int n_items)
{
    int item = blockIdx.x * 4 + (threadIdx.x >> 6);
    int lane = threadIdx.x & 63;
    if (item >= n_items) return;
    int off = offsets[item];
    int cnt = counts[item];
    float sum = 0.f;
    for (int e = 0; e < cnt; ++e) {
        int s = csr_src[off + e];
        sum += user_embed[(size_t)s * EMBED_DIM + lane];
    }
    float denom = (cnt > 0) ? (float)cnt : 1.0f;
    out[(size_t)item * EMBED_DIM + lane] = sum / denom;
}

// ---------------- tier-3: atomic fallback ----------------

__global__ __launch_bounds__(256) void scatter_mean_accum(
    const float* __restrict__ user_embed,
    const int* __restrict__ edge_src,
    const int* __restrict__ edge_dst,
    float* __restrict__ sums, float* __restrict__ counts, int num_edges)
{
    const int edge = blockIdx.x * (blockDim.x >> 6) + (threadIdx.x >> 6);
    const int lane = threadIdx.x & 63;
    if (edge >= num_edges) return;
    const int s = edge_src[edge];
    const int d = edge_dst[edge];
    atomicAdd(&sums[(size_t)d * EMBED_DIM + lane],
              user_embed[(size_t)s * EMBED_DIM + lane]);
    if (lane == 0) atomicAdd(&counts[d], 1.0f);
}

__global__ __launch_bounds__(256) void divide_by_count(
    float* __restrict__ out, const float* __restrict__ counts, int n)
{
    const int idx = blockIdx.x * blockDim.x + threadIdx.x;
    if (idx >= n) return;
    out[idx] = out[idx] / fmaxf(counts[idx >> 6], 1.0f);
}

// ---------------- launcher ----------------

extern "C" void kernel_launch(void* const* d_in, const int* in_sizes, int n_in,
                              void* d_out, int out_size, void* d_ws, size_t ws_size,
                              hipStream_t stream)
{
    const float* user_embed = (const float*)d_in[0];
    const int* edge_src = (const int*)d_in[2];
    const int* edge_dst = (const int*)d_in[3];
    const int num_edges = in_sizes[2];
    float* out = (float*)d_out;

    const int eb = (num_edges + 255) / 256 > 0 ? (num_edges + 255) / 256 : 1;

    // ---- tier 0: bucketed fused pipeline ----
    // ws: cur (NB*8*4) | spill_n (64B) | spill (64K * 8B) | storage (NB*8*subcap*4)
    {
        const size_t cur_b   = (size_t)NB_BUCKET * NSUB * 4;   // 62528
        const size_t hdr_b   = 64;
        const int    spill_cap = 65536;
        const size_t spill_b = (size_t)spill_cap * 8;
        const size_t fixed   = cur_b + hdr_b + spill_b;
        long long avail = (long long)ws_size - (long long)fixed;
        long long sc = (avail > 0) ? avail / ((long long)NB_BUCKET * NSUB * 4) : 0;
        if (sc > 512) sc = 512;
        if (sc >= 192) {
            const int subcap = (int)sc;     // Poisson(128), sd 11 -> >=192 is >5.8 sigma
            char* ws = (char*)d_ws;
            int*      cur     = (int*)ws;
            int*      spill_n = (int*)(ws + cur_b);
            uint2*    spill   = (uint2*)(ws + cur_b + hdr_b);
            unsigned* storage = (unsigned*)(ws + fixed);

            (void)hipMemsetAsync(ws, 0, cur_b + hdr_b, stream);  // cur + spill_n
            bin_edges<<<eb, 256, 0, stream>>>(
                edge_src, edge_dst, num_edges, cur, storage, subcap,
                spill, spill_n, spill_cap);
            bucket_reduce<<<NB_BUCKET, 256, 0, stream>>>(
                user_embed, cur, storage, subcap, spill, spill_n, spill_cap,
                out, NUM_ITEM);
            return;
        }
    }

    // ---- tier 2: exact CSR pipeline ----
    const int NB = (NUM_ITEM + 255) / 256;
    const size_t counts_b   = (size_t)NUM_ITEM * 4;
    const size_t offsets_b  = (size_t)NUM_ITEM * 4;
    const size_t cursor_b   = (size_t)NUM_ITEM * 4;
    const size_t partials_b = 2048 * 4;
    const size_t csr_b      = (size_t)num_edges * 4;
    const size_t needed = counts_b + offsets_b + cursor_b + partials_b + csr_b;

    if (ws_size >= needed) {
        char* ws = (char*)d_ws;
        int* counts   = (int*)ws;                         ws += counts_b;
        int* offsets  = (int*)ws;                         ws += offsets_b;
        int* cursor   = (int*)ws;                         ws += cursor_b;
        int* partials = (int*)ws;                         ws += partials_b;
        int* csr_src  = (int*)ws;

        (void)hipMemsetAsync(counts, 0, counts_b, stream);
        histogram_dst<<<eb, 256, 0, stream>>>(edge_dst, num_edges, counts);
        block_sums<<<NB, 256, 0, stream>>>(counts, NUM_ITEM, partials);
        scan_partials<<<1, 256, 0, stream>>>(partials, NB);
        make_offsets<<<NB, 256, 0, stream>>>(counts, partials, NUM_ITEM, offsets, cursor);
        scatter_csr<<<eb, 256, 0, stream>>>(edge_src, edge_dst, num_edges, cursor, csr_src);
        gather_mean<<<(NUM_ITEM + 3) / 4, 256, 0, stream>>>(
            user_embed, csr_src, offsets, counts, out, NUM_ITEM);
    } else {
        // ---- tier 3: atomic scatter ----
        float* counts = (float*)d_ws;
        (void)hipMemsetAsync(d_out, 0, (size_t)NUM_ITEM * EMBED_DIM * sizeof(float), stream);
        (void)hipMemsetAsync(d_ws, 0, (size_t)NUM_ITEM * sizeof(float), stream);
        const int blocks = (num_edges + 3) / 4;
        scatter_mean_accum<<<blocks, 256, 0, stream>>>(
            user_embed, edge_src, edge_dst, out, counts, num_edges);
        const int n = NUM_ITEM * EMBED_DIM;
        divide_by_count<<<(n + 255) / 256, 256, 0, stream>>>(out, counts, n);
    }
}

// Round 5
// 1117.587 us; speedup vs baseline: 1.0004x; 1.0004x over previous
//
#include <hip/hip_runtime.h>

#define NUM_ITEM 500000
#define EMBED_DIM 64
#define SPAN 64                                   // items per bucket
#define NBK ((NUM_ITEM + SPAN - 1) / SPAN)        // 7813
#define NSUB 8                                    // XCD-local sublists per bucket

typedef float f4_native __attribute__((ext_vector_type(4)));

// ---------------- tier-0: bucketed fused pipeline ----------------

// Pass 1: bin edges by dst>>6 into (bucket, blockIdx&7) sublists.
// Record packed to 4B: (d & 63) << 24 | s  (valid: s < 2^24).
// Each XCD's write frontier = its own 7813 sublist tails (~0.5MB, L2-resident)
// -> writebacks ~= payload (8MB), not 128MB like the random pad scatter.
// Overflow goes to a spill list sized >= num_edges: NO record can be lost,
// exact for any input distribution.
__global__ __launch_bounds__(256) void bin_edges(
    const int* __restrict__ edge_src, const int* __restrict__ edge_dst,
    int num_edges, int* __restrict__ cur, unsigned* __restrict__ storage,
    int subcap, uint2* __restrict__ spill, int* __restrict__ spill_n)
{
    int e = blockIdx.x * 256 + threadIdx.x;
    if (e >= num_edges) return;
    int d = edge_dst[e];
    int s = edge_src[e];
    int idx = ((d >> 6) << 3) + (blockIdx.x & 7);
    int pos = atomicAdd(&cur[idx], 1);
    if (pos < subcap) {
        storage[(size_t)idx * subcap + pos] =
            ((unsigned)(d & 63) << 24) | (unsigned)s;
    } else {
        int o = atomicAdd(spill_n, 1);
        spill[o] = make_uint2((unsigned)d, (unsigned)s);   // cap >= num_edges
    }
}

// Pass 2: one 256-thread WG per 64-item bucket. acc = 16.6KB LDS -> 8 WG/CU
// (thread-cap), grid 7813. Wave w owns sublists {2w, 2w+1}: 4-way parallel
// over sublists + 8-deep gather ILP per wave. lane = dim, so ds atomics are
// 2-way/bank (free) and row gathers are 256B coalesced.
__global__ __launch_bounds__(256) void bucket_reduce(
    const float* __restrict__ user_embed, const int* __restrict__ cur,
    const unsigned* __restrict__ storage, int subcap,
    const uint2* __restrict__ spill, const int* __restrict__ spill_n,
    int spill_cap, float* __restrict__ out, int n_items)
{
    __shared__ float acc[SPAN * EMBED_DIM];   // 16 KB
    __shared__ int   lcnt[SPAN];
    const int b    = blockIdx.x;
    const int tid  = threadIdx.x;
    const int wid  = tid >> 6;
    const int lane = tid & 63;

    f4_native z = 0.0f;
    f4_native* a4 = (f4_native*)acc;
#pragma unroll
    for (int i = 0; i < (SPAN * EMBED_DIM / 4) / 256; ++i)   // 4 iters
        a4[tid + i * 256] = z;
    if (tid < SPAN) lcnt[tid] = 0;
    __syncthreads();

    const int item0 = b * SPAN;
#pragma unroll
    for (int ss = 0; ss < 2; ++ss) {
        const int idx = (b << 3) + ((wid << 1) | ss);
        int ne = cur[idx]; if (ne > subcap) ne = subcap;
        const unsigned* base = storage + (size_t)idx * subcap;
        int e = 0;
        for (; e + 7 < ne; e += 8) {            // 8 independent gathers in flight
            unsigned r[8]; float v[8];
#pragma unroll
            for (int k = 0; k < 8; ++k) r[k] = base[e + k];
#pragma unroll
            for (int k = 0; k < 8; ++k)
                v[k] = user_embed[((size_t)(r[k] & 0xFFFFFFu) << 6) + lane];
#pragma unroll
            for (int k = 0; k < 8; ++k) {
                int dl = r[k] >> 24;
                atomicAdd(&acc[(dl << 6) + lane], v[k]);
                if (lane == 0) atomicAdd(&lcnt[dl], 1);
            }
        }
        for (; e < ne; ++e) {
            unsigned r = base[e];
            float v = user_embed[((size_t)(r & 0xFFFFFFu) << 6) + lane];
            int dl = r >> 24;
            atomicAdd(&acc[(dl << 6) + lane], v);
            if (lane == 0) atomicAdd(&lcnt[dl], 1);
        }
    }

    // spill entries (zero for non-pathological inputs) — exactness guarantee
    int ns = *spill_n; if (ns > spill_cap) ns = spill_cap;
    for (int i = wid; i < ns; i += 4) {
        uint2 p = spill[i];
        int d = (int)p.x;
        if (d >= item0 && d < item0 + SPAN) {
            int dl = d - item0;
            float v = user_embed[((size_t)p.y << 6) + lane];
            atomicAdd(&acc[(dl << 6) + lane], v);
            if (lane == 0) atomicAdd(&lcnt[dl], 1);
        }
    }
    __syncthreads();

    for (int it = wid; it < SPAN; it += 4) {
        int item = item0 + it;
        if (item >= n_items) break;              // wave-uniform
        float c = (float)lcnt[it];
        float v = acc[(it << 6) + lane] / fmaxf(c, 1.0f);
        // 64 lanes x 4B = one 256B line; nontemporal: 128MB output stream
        // must not evict user rows / sublist tails from L2
        __builtin_nontemporal_store(v, &out[((size_t)item << 6) + lane]);
    }
}

// ---------------- tier-2: exact CSR pipeline (fallback) ----------------

__global__ __launch_bounds__(256) void histogram_dst(
    const int* __restrict__ edge_dst, int num_edges, int* __restrict__ counts)
{
    int e = blockIdx.x * blockDim.x + threadIdx.x;
    if (e >= num_edges) return;
    atomicAdd(&counts[edge_dst[e]], 1);
}

__global__ __launch_bounds__(256) void block_sums(
    const int* __restrict__ counts, int n, int* __restrict__ partials)
{
    __shared__ int red[256];
    int i = blockIdx.x * 256 + threadIdx.x;
    red[threadIdx.x] = (i < n) ? counts[i] : 0;
    __syncthreads();
    for (int s = 128; s > 0; s >>= 1) {
        if (threadIdx.x < (unsigned)s) red[threadIdx.x] += red[threadIdx.x + s];
        __syncthreads();
    }
    if (threadIdx.x == 0) partials[blockIdx.x] = red[0];
}

__global__ __launch_bounds__(256) void scan_partials(int* __restrict__ partials, int nb)
{
    __shared__ int tmp[256];
    __shared__ int carry_s;
    if (threadIdx.x == 0) carry_s = 0;
    __syncthreads();
    for (int base = 0; base < nb; base += 256) {
        int i = base + threadIdx.x;
        int v = (i < nb) ? partials[i] : 0;
        tmp[threadIdx.x] = v;
        __syncthreads();
        for (int off = 1; off < 256; off <<= 1) {
            int t = (threadIdx.x >= (unsigned)off) ? tmp[threadIdx.x - off] : 0;
            __syncthreads();
            tmp[threadIdx.x] += t;
            __syncthreads();
        }
        int incl = tmp[threadIdx.x];
        int c = carry_s;
        if (i < nb) partials[i] = incl - v + c;
        __syncthreads();
        if (threadIdx.x == 255) carry_s = c + tmp[255];
        __syncthreads();
    }
}

__global__ __launch_bounds__(256) void make_offsets(
    const int* __restrict__ counts, const int* __restrict__ partials, int n,
    int* __restrict__ offsets, int* __restrict__ cursor)
{
    __shared__ int tmp[256];
    int i = blockIdx.x * 256 + threadIdx.x;
    int v = (i < n) ? counts[i] : 0;
    tmp[threadIdx.x] = v;
    __syncthreads();
    for (int off = 1; off < 256; off <<= 1) {
        int t = (threadIdx.x >= (unsigned)off) ? tmp[threadIdx.x - off] : 0;
        __syncthreads();
        tmp[threadIdx.x] += t;
        __syncthreads();
    }
    int excl = tmp[threadIdx.x] - v + partials[blockIdx.x];
    if (i < n) { offsets[i] = excl; cursor[i] = excl; }
}

__global__ __launch_bounds__(256) void scatter_csr(
    const int* __restrict__ edge_src, const int* __restrict__ edge_dst,
    int num_edges, int* __restrict__ cursor, int* __restrict__ csr_src)
{
    int e = blockIdx.x * blockDim.x + threadIdx.x;
    if (e >= num_edges) return;
    int d = edge_dst[e];
    int pos = atomicAdd(&cursor[d], 1);
    csr_src[pos] = edge_src[e];
}

__global__ __launch_bounds__(256) void gather_mean(
    const float* __restrict__ user_embed, const int* __restrict__ csr_src,
    const int* __restrict__ offsets, const int* __restrict__ counts,
    float* __restrict__ out, int n_items)
{
    int item = blockIdx.x * 4 + (threadIdx.x >> 6);
    int lane = threadIdx.x & 63;
    if (item >= n_items) return;
    int off = offsets[item];
    int cnt = counts[item];
    float sum = 0.f;
    for (int e = 0; e < cnt; ++e) {
        int s = csr_src[off + e];
        sum += user_embed[(size_t)s * EMBED_DIM + lane];
    }
    float denom = (cnt > 0) ? (float)cnt : 1.0f;
    out[(size_t)item * EMBED_DIM + lane] = sum / denom;
}

// ---------------- tier-3: atomic fallback ----------------

__global__ __launch_bounds__(256) void scatter_mean_accum(
    const float* __restrict__ user_embed,
    const int* __restrict__ edge_src,
    const int* __restrict__ edge_dst,
    float* __restrict__ sums, float* __restrict__ counts, int num_edges)
{
    const int edge = blockIdx.x * (blockDim.x >> 6) + (threadIdx.x >> 6);
    const int lane = threadIdx.x & 63;
    if (edge >= num_edges) return;
    const int s = edge_src[edge];
    const int d = edge_dst[edge];
    atomicAdd(&sums[(size_t)d * EMBED_DIM + lane],
              user_embed[(size_t)s * EMBED_DIM + lane]);
    if (lane == 0) atomicAdd(&counts[d], 1.0f);
}

__global__ __launch_bounds__(256) void divide_by_count(
    float* __restrict__ out, const float* __restrict__ counts, int n)
{
    const int idx = blockIdx.x * blockDim.x + threadIdx.x;
    if (idx >= n) return;
    out[idx] = out[idx] / fmaxf(counts[idx >> 6], 1.0f);
}

// ---------------- launcher ----------------

extern "C" void kernel_launch(void* const* d_in, const int* in_sizes, int n_in,
                              void* d_out, int out_size, void* d_ws, size_t ws_size,
                              hipStream_t stream)
{
    const float* user_embed = (const float*)d_in[0];
    const int* edge_src = (const int*)d_in[2];
    const int* edge_dst = (const int*)d_in[3];
    const int num_edges = in_sizes[2];
    float* out = (float*)d_out;

    const int eb = (num_edges + 255) / 256 > 0 ? (num_edges + 255) / 256 : 1;

    // ---- tier 0: bucketed fused pipeline ----
    // ws: cur (NBK*8*4 ~ 250KB) | spill_n (64B) | spill (num_edges*8B) | storage
    {
        const size_t cur_b   = (size_t)NBK * NSUB * 4;
        const size_t hdr_b   = 64;
        const size_t spill_b = (size_t)num_edges * 8;     // cap >= num_edges: lossless
        const size_t fixed   = cur_b + hdr_b + spill_b;
        long long avail = (long long)ws_size - (long long)fixed;
        long long sc = (avail > 0) ? avail / ((long long)NBK * NSUB * 4) : 0;
        if (sc > 128) sc = 128;
        if (sc >= 64) {                                   // mean 32, sd 5.7
            const int subcap = (int)sc;
            char* ws = (char*)d_ws;
            int*      cur     = (int*)ws;
            int*      spill_n = (int*)(ws + cur_b);
            uint2*    spill   = (uint2*)(ws + cur_b + hdr_b);
            unsigned* storage = (unsigned*)(ws + fixed);

            (void)hipMemsetAsync(ws, 0, cur_b + hdr_b, stream);  // cur + spill_n
            bin_edges<<<eb, 256, 0, stream>>>(
                edge_src, edge_dst, num_edges, cur, storage, subcap,
                spill, spill_n);
            bucket_reduce<<<NBK, 256, 0, stream>>>(
                user_embed, cur, storage, subcap, spill, spill_n,
                num_edges, out, NUM_ITEM);
            return;
        }
    }

    // ---- tier 2: exact CSR pipeline ----
    const int NB = (NUM_ITEM + 255) / 256;
    const size_t counts_b   = (size_t)NUM_ITEM * 4;
    const size_t offsets_b  = (size_t)NUM_ITEM * 4;
    const size_t cursor_b   = (size_t)NUM_ITEM * 4;
    const size_t partials_b = 2048 * 4;
    const size_t csr_b      = (size_t)num_edges * 4;
    const size_t needed = counts_b + offsets_b + cursor_b + partials_b + csr_b;

    if (ws_size >= needed) {
        char* ws = (char*)d_ws;
        int* counts   = (int*)ws;                         ws += counts_b;
        int* offsets  = (int*)ws;                         ws += offsets_b;
        int* cursor   = (int*)ws;                         ws += cursor_b;
        int* partials = (int*)ws;                         ws += partials_b;
        int* csr_src  = (int*)ws;

        (void)hipMemsetAsync(counts, 0, counts_b, stream);
        histogram_dst<<<eb, 256, 0, stream>>>(edge_dst, num_edges, counts);
        block_sums<<<NB, 256, 0, stream>>>(counts, NUM_ITEM, partials);
        scan_partials<<<1, 256, 0, stream>>>(partials, NB);
        make_offsets<<<NB, 256, 0, stream>>>(counts, partials, NUM_ITEM, offsets, cursor);
        scatter_csr<<<eb, 256, 0, stream>>>(edge_src, edge_dst, num_edges, cursor, csr_src);
        gather_mean<<<(NUM_ITEM + 3) / 4, 256, 0, stream>>>(
            user_embed, csr_src, offsets, counts, out, NUM_ITEM);
    } else {
        // ---- tier 3: atomic scatter ----
        float* counts = (float*)d_ws;
        (void)hipMemsetAsync(d_out, 0, (size_t)NUM_ITEM * EMBED_DIM * sizeof(float), stream);
        (void)hipMemsetAsync(d_ws, 0, (size_t)NUM_ITEM * sizeof(float), stream);
        const int blocks = (num_edges + 3) / 4;
        scatter_mean_accum<<<blocks, 256, 0, stream>>>(
            user_embed, edge_src, edge_dst, out, counts, num_edges);
        const int n = NUM_ITEM * EMBED_DIM;
        divide_by_count<<<(n + 255) / 256, 256, 0, stream>>>(out, counts, n);
    }
}